// Round 11
// baseline (154.235 us; speedup 1.0000x reference)
//
#include <hip/hip_runtime.h>
#include <hip/hip_bf16.h>
#include <math.h>

#define IN_DIM 256
#define HD     512   // NUM_HEADS * OUT_DIM
#define NHEADS 8
#define DH     64
#define NSEQ   1024
#define BATCH  8

#define QSCALE 0.18033688011112042f   // 0.125 * log2(e): S in log2 domain

typedef unsigned short u16;
typedef unsigned int   u32;
typedef short bf16x8 __attribute__((ext_vector_type(8)));
typedef float f32x4  __attribute__((ext_vector_type(4)));
typedef float f32x16 __attribute__((ext_vector_type(16)));
typedef unsigned int u32x2 __attribute__((ext_vector_type(2)));

#if __has_builtin(__builtin_amdgcn_exp2f)
#define EXP2(x) __builtin_amdgcn_exp2f(x)
#else
#define EXP2(x) __expf(0.69314718056f * (x))
#endif

static __device__ __forceinline__ u16 f2bf(float x) {
    u32 u = __builtin_bit_cast(u32, x);
    u += 0x7FFFu + ((u >> 16) & 1u);     // RNE
    return (u16)(u >> 16);
}
static __device__ __forceinline__ u32 pk(u16 a, u16 b) {
    return (u32)a | ((u32)b << 16);
}
static __device__ __forceinline__ u32 cvtpk(float a, float b) {
    __hip_bfloat162 t = __float22bfloat162_rn(make_float2(a, b));
    u32 r; __builtin_memcpy(&r, &t, 4);
    return r;
}
// 16 bf16 (two uint4) -> f32x16 C-init
static __device__ __forceinline__ f32x16 maskinit(uint4 a, uint4 b) {
    f32x16 c;
    u32 ws[8] = {a.x, a.y, a.z, a.w, b.x, b.y, b.z, b.w};
#pragma unroll
    for (int i = 0; i < 8; ++i) {
        c[2 * i]     = __builtin_bit_cast(float, ws[i] << 16);
        c[2 * i + 1] = __builtin_bit_cast(float, ws[i] & 0xFFFF0000u);
    }
    return c;
}

// permlane32_swap: a' = [a_lo | b_lo], b' = [a_hi | b_hi] (32-lane rows)
static __device__ __forceinline__ void pswap(u32 &a, u32 &b) {
#if __has_builtin(__builtin_amdgcn_permlane32_swap)
    u32x2 r = __builtin_amdgcn_permlane32_swap(a, b, false, false);
    a = r.x; b = r.y;
#else
    const bool hi = (threadIdx.x & 32) != 0;
    u32 as = (u32)__shfl_xor((int)a, 32, 64);
    u32 bs = (u32)__shfl_xor((int)b, 32, 64);
    u32 na = hi ? bs : a;
    u32 nb = hi ? b  : as;
    a = na; b = nb;
#endif
}

#define MFMA32(a, b, c) __builtin_amdgcn_mfma_f32_32x32x16_bf16(a, b, c, 0, 0, 0)

// async global->LDS, 16 B/lane (still used by the GEMM kernel)
#define GLOAD16(G, L)                                                          \
    __builtin_amdgcn_global_load_lds(                                          \
        (const __attribute__((address_space(1))) unsigned int*)(const void*)(G),\
        (__attribute__((address_space(3))) unsigned int*)(void*)(L), 16, 0, 0)

// 16B frag load from 4B-aligned LDS (132B-skewed rows): two 8B accesses.
static __device__ __forceinline__ bf16x8 ldfrag(const u16* p) {
    uint2 lo, hi;
    __builtin_memcpy(&lo, p, 8);
    __builtin_memcpy(&hi, p + 4, 8);
    uint4 u;
    u.x = lo.x; u.y = lo.y; u.z = hi.x; u.w = hi.y;
    return __builtin_bit_cast(bf16x8, u);
}
// 16B store to 4B-aligned LDS: two 8B accesses.
static __device__ __forceinline__ void st16(u16* p, uint4 v) {
    uint2 a, b;
    a.x = v.x; a.y = v.y; b.x = v.z; b.y = v.w;
    __builtin_memcpy(p, &a, 8);
    __builtin_memcpy(p + 4, &b, 8);
}

// exp2 of ONE 32-key S^T tile, tree-sum, pack to bf16, permlane-exchange:
// pb[0], pb[1] are the B-frags for the two 16-key MFMA steps of this tile.
static __device__ __forceinline__ float sm_pack_half(const f32x16 st, bf16x8* pb) {
    float p[16];
#pragma unroll
    for (int r = 0; r < 16; ++r) p[r] = EXP2(st[r]);
    float t = (((p[0] + p[1]) + (p[2] + p[3])) + ((p[4] + p[5]) + (p[6] + p[7])))
            + (((p[8] + p[9]) + (p[10] + p[11])) + ((p[12] + p[13]) + (p[14] + p[15])));
    uint4 w0, w1;
    w0.x = cvtpk(p[0], p[1]);   w0.y = cvtpk(p[2], p[3]);
    w0.z = cvtpk(p[4], p[5]);   w0.w = cvtpk(p[6], p[7]);
    w1.x = cvtpk(p[8], p[9]);   w1.y = cvtpk(p[10], p[11]);
    w1.z = cvtpk(p[12], p[13]); w1.w = cvtpk(p[14], p[15]);
    pswap(w0.x, w1.x); pswap(w0.y, w1.y); pswap(w0.z, w1.z); pswap(w0.w, w1.w);
    pb[0] = __builtin_bit_cast(bf16x8, w0);
    pb[1] = __builtin_bit_cast(bf16x8, w1);
    return t;
}

// ============================================================
// W transpose + h->bf16: 224 blocks.
// ============================================================
__global__ __launch_bounds__(256)
void wtrans_kernel(const float* __restrict__ Wq, const float* __restrict__ Wk,
                   const float* __restrict__ Wv, const float* __restrict__ h,
                   u16* __restrict__ Wt, u16* __restrict__ hb)
{
    __shared__ float tile[64 * 65];
    const int bid = blockIdx.x, tid = threadIdx.x;

    if (bid >= 96) {
        const int ab = bid - 96;
        const float4* hs = (const float4*)h;
        uint2* hd = (uint2*)hb;
        const int base = ab * 4096 + tid;
#pragma unroll
        for (int j = 0; j < 16; ++j) {
            float4 v = hs[base + j * 256];
            uint2 o;
            o.x = cvtpk(v.x, v.y);
            o.y = cvtpk(v.z, v.w);
            hd[base + j * 256] = o;
        }
        return;
    }

    const int k0 = (bid & 3) * 64, n0 = ((bid >> 2) & 7) * 64, wsel = bid >> 5;
    const float* W = (wsel == 0) ? Wq : (wsel == 1) ? Wk : Wv;
    u16* Out = Wt + (size_t)wsel * HD * IN_DIM;

    const int r = tid >> 2, c0 = (tid & 3) * 16;
#pragma unroll
    for (int j = 0; j < 16; j += 4) {
        float4 v = *(const float4*)(W + (size_t)(k0 + r) * HD + n0 + c0 + j);
        tile[r * 65 + c0 + j + 0] = v.x; tile[r * 65 + c0 + j + 1] = v.y;
        tile[r * 65 + c0 + j + 2] = v.z; tile[r * 65 + c0 + j + 3] = v.w;
    }
    __syncthreads();
    const int n = tid >> 2, ks = (tid & 3) * 16;
    u16 o[16];
#pragma unroll
    for (int j = 0; j < 16; ++j) o[j] = f2bf(tile[(ks + j) * 65 + n]);
    uint4 u0, u1;
    u0.x = pk(o[0], o[1]);   u0.y = pk(o[2], o[3]);
    u0.z = pk(o[4], o[5]);   u0.w = pk(o[6], o[7]);
    u1.x = pk(o[8], o[9]);   u1.y = pk(o[10], o[11]);
    u1.z = pk(o[12], o[13]); u1.w = pk(o[14], o[15]);
    u16* dst = Out + (size_t)(n0 + n) * IN_DIM + k0 + ks;
    *(uint4*)(dst) = u0;
    *(uint4*)(dst + 8) = u1;
}

// ============================================================
// Fused QKV GEMM + mask build (unchanged from round 9).
// ============================================================
__global__ __launch_bounds__(256, 2)
void gemm_mask_kernel(const u16* __restrict__ hb, const u16* __restrict__ Wt,
                      const int* __restrict__ adj,
                      const float* __restrict__ bq, const float* __restrict__ bk,
                      const float* __restrict__ bv,
                      u16* __restrict__ Qg, u16* __restrict__ Kg,
                      u16* __restrict__ Vtg, u16* __restrict__ Madd3)
{
    __shared__ __align__(16) u16 lds[32768];
    const int tid = threadIdx.x;

    if (blockIdx.y >= 8) {
        int* tile = (int*)lds;               // [64][65] ints
        const int abid = (blockIdx.y - 8) * 128 + blockIdx.x;   // 0..255
        const int tR = abid >> 4, tC = abid & 15;
        const int r = tid >> 2, cg = (tid & 3) * 16;
        const int* src = adj + (size_t)(tR * 64 + r) * NSEQ + tC * 64 + cg;
#pragma unroll
        for (int j = 0; j < 16; j += 4) {
            int4 a = *(const int4*)(src + j);
            tile[r * 65 + cg + j + 0] = a.x; tile[r * 65 + cg + j + 1] = a.y;
            tile[r * 65 + cg + j + 2] = a.z; tile[r * 65 + cg + j + 3] = a.w;
        }
        __syncthreads();
        const int q = tid >> 2, g4 = tid & 3, p0 = g4 * 16;
        u16 o[16];
#pragma unroll
        for (int j = 0; j < 16; ++j) {
            const int p = p0 + j;
            const int c = 32 * (p >> 5) + (p & 3) + 4 * ((p >> 4) & 1) + 8 * ((p >> 2) & 3);
            o[j] = (tile[q * 65 + c] == 0) ? (u16)0xFF7F : (u16)0;
        }
        uint4 u0, u1;
        u0.x = pk(o[0], o[1]);   u0.y = pk(o[2], o[3]);
        u0.z = pk(o[4], o[5]);   u0.w = pk(o[6], o[7]);
        u1.x = pk(o[8], o[9]);   u1.y = pk(o[10], o[11]);
        u1.z = pk(o[12], o[13]); u1.w = pk(o[14], o[15]);
        u16* dst = Madd3 + ((size_t)(tC * 4 + g4) * 1024 + tR * 64 + q) * 16;
        *(uint4*)(dst) = u0;
        *(uint4*)(dst + 8) = u1;
        return;
    }

    const int m0 = blockIdx.x * 64;
    const int hh = blockIdx.y;
    const int n0 = hh * 64;

    const int w = tid >> 6, lane = tid & 63;
    const int l31 = lane & 31, half = lane >> 5;
    const int mh = w & 1, nh = w >> 1;
    const int s7 = l31 & 7;

    const int lrow = lane >> 3, lgran = (lane & 7) ^ lrow;
    const int r0 = w * 16;
    const u16* ag = hb + (size_t)(m0 + r0 + lrow) * IN_DIM + lgran * 8;
    const u16* bg = Wt + (size_t)(n0 + r0 + lrow) * IN_DIM + lgran * 8;

#define STAGE_G(BUF, KK)                                                        \
    do {                                                                        \
        u16* a0 = lds + (BUF) * 4096 + r0 * 64;                                 \
        u16* b0 = lds + 8192 + (BUF) * 12288 + r0 * 64;                         \
        GLOAD16(ag + (KK) * 64,                                    a0);         \
        GLOAD16(ag + (KK) * 64 + 8 * IN_DIM,                       a0 + 512);   \
        GLOAD16(bg + (KK) * 64,                                    b0);         \
        GLOAD16(bg + (KK) * 64 + 8 * IN_DIM,                       b0 + 512);   \
        GLOAD16(bg + (KK) * 64 + (size_t)HD * IN_DIM,              b0 + 4096);  \
        GLOAD16(bg + (KK) * 64 + (size_t)HD * IN_DIM + 8 * IN_DIM, b0 + 4608);  \
        GLOAD16(bg + (KK) * 64 + (size_t)2 * HD * IN_DIM,          b0 + 8192);  \
        GLOAD16(bg + (KK) * 64 + (size_t)2 * HD * IN_DIM + 8 * IN_DIM, b0 + 8704); \
    } while (0)

    f32x16 acc[3] = {};   // Q, K, V 32x32 tiles
    const int arow = (32 * mh + l31) * 64;
    const int brow = (32 * nh + l31) * 64;

    STAGE_G(0, 0);
#pragma unroll
    for (int kk = 0; kk < 4; ++kk) {
        const int cur = kk & 1;
        __syncthreads();
        if (kk < 3) STAGE_G(1 - cur, kk + 1);
        const u16* Ac = lds + cur * 4096;
        const u16* Bc = lds + 8192 + cur * 12288;
#pragma unroll
        for (int s = 0; s < 4; ++s) {
            const int g = ((s * 2 + half) ^ s7) * 8;
            bf16x8 a = *(const bf16x8*)&Ac[arow + g];
#pragma unroll
            for (int wh = 0; wh < 3; ++wh) {
                bf16x8 b = *(const bf16x8*)&Bc[wh * 4096 + brow + g];
                acc[wh] = __builtin_amdgcn_mfma_f32_32x32x16_bf16(a, b, acc[wh], 0, 0, 0);
            }
        }
    }
#undef STAGE_G

    for (int which = 0; which < 2; ++which) {
        u16* T = lds;   // [64][72]
        const float* bias = (which == 0) ? bq : bk;
        u16* Out = (which == 0) ? Qg : Kg;
        const float scale = (which == 0) ? QSCALE : 1.0f;
        const float bvv = bias[n0 + 32 * nh + l31];
        __syncthreads();
#pragma unroll
        for (int r = 0; r < 16; ++r) {
            const int row = 32 * mh + 4 * half + (r & 3) + 8 * (r >> 2);
            T[row * 72 + 32 * nh + l31] = f2bf((acc[which][r] + bvv) * scale);
        }
        __syncthreads();
        const int row = tid >> 2, qc = (tid & 3) * 16;
        u16* dst = Out + (size_t)(m0 + row) * HD + n0 + qc;
        const u16* srcT = &T[row * 72 + qc];
        *(uint4*)(dst)     = *(const uint4*)(srcT);
        *(uint4*)(dst + 8) = *(const uint4*)(srcT + 8);
    }

    {
        u16* T = lds;   // [64][72]  [d][pos]
        const int d = 32 * nh + l31;
        const float bvv = bv[n0 + d];
        __syncthreads();
#pragma unroll
        for (int g = 0; g < 4; ++g) {
            ushort4 o;
            o.x = f2bf(acc[2][4 * g + 0] + bvv);
            o.y = f2bf(acc[2][4 * g + 1] + bvv);
            o.z = f2bf(acc[2][4 * g + 2] + bvv);
            o.w = f2bf(acc[2][4 * g + 3] + bvv);
            *(ushort4*)&T[d * 72 + 32 * mh + 16 * half + 4 * g] = o;
        }
        __syncthreads();
        const int b = m0 >> 10, nloc = m0 & 1023;
        const int dd = tid >> 2, c = (tid & 3) * 16;
        u16* dst = Vtg + ((size_t)(b * NHEADS + hh) * DH + dd) * NSEQ + nloc + c;
        *(uint4*)(dst)     = *(uint4*)&T[dd * 72 + c];
        *(uint4*)(dst + 8) = *(uint4*)&T[dd * 72 + c + 8];
    }
}

// ============================================================
// Fused masked attention, 32x32x16 MFMA, no-max softmax.
// Round-11: LDS bank-conflict elimination via 4-byte row skew.
//  Diagnostic (r10, z=2) showed LDS pipe ~51% of the chunk wall with
//  exactly +4 conflict-cy per ds_read_b128: 128B row stride => bank
//  group = 16B-slot only (8 groups) => structural 4-way alias that NO
//  16B-granule swizzle can fix (and global_load_lds can't express
//  sub-16B skews). Fix: K/V tiles as [64][66] u16 (132B rows, 4B skew):
//  bank(row r, granule g, half h) = (r + 8s + 4h) mod 32 -> all 32
//  banks, 2 lanes/bank (free, m136). Frags read/written as 2x8B
//  (4B-aligned-legal); read swizzle XOR dropped (granules linear).
//  Staging: register path (16 VGPR, distance-2), no DMA.
//  Occupancy: 512 thr, 4 waves/SIMD (VGPR ~85 <= 128), LDS 66 KB
//  static -> 2 blocks/CU (135 KB <= 160 KB).
//  Keeps: team key-split, qrep=1, half-chunk softmax, permlane P,
//  setprio MFMA clusters, q-innermost coalesced mask planes. z=1.
// ============================================================
__global__ __launch_bounds__(512, 4)
void attn_kernel(const u16* __restrict__ Madd3, const u16* __restrict__ Qg,
                 const u16* __restrict__ Kg, const u16* __restrict__ Vtg,
                 float* __restrict__ out)
{
    // [team][buf][K=0/V=1][64 rows x 66 u16] ; 67,584 B total
    __shared__ __align__(16) u16 KV[2][2][2][4224];

    const int tid = threadIdx.x;
    const int w = tid >> 6, lane = tid & 63;
    const int team = w >> 2, j = w & 3;
    const int l31 = lane & 31, half = lane >> 5;
    const int bh = blockIdx.x, qt = blockIdx.y;
    const int b = bh >> 3;
    const int n0 = qt * 128;
    const size_t rowbase = (size_t)b * NSEQ;
    const int colbase = (bh & 7) * DH;
    const int qA = j * 32 + l31;          // block-local q row (wave's tile)
    const int cbase = team * 8;           // team's first key chunk

    // Q B-frags (bf16, pre-scaled): B[k][q=l31]
    const u16* qga = Qg + (rowbase + n0 + qA) * HD + colbase;
    bf16x8 qb[4];
#pragma unroll
    for (int s = 0; s < 4; ++s)
        qb[s] = *(const bf16x8*)(qga + s * 16 + half * 8);

    // ---- register staging geometry (256 thr per team) ----
    // lane ttid -> rows srow, srow+32 ; granule sg (16B each)
    const int ttid = tid & 255;
    const int srow = ttid >> 3, sg = ttid & 7;
    const u16* kst = Kg + (rowbase + cbase * 64 + srow) * HD + colbase + sg * 8;
    const u16* vst = Vtg + ((size_t)bh * DH + srow) * NSEQ + cbase * 64 + sg * 8;
    const int wi0 = srow * 66 + sg * 8;          // LDS write indices
    const int wi1 = (srow + 32) * 66 + sg * 8;

    uint4 kr0, kr1, vr0, vr1;                    // 16 staging VGPRs
#define LOADR(CH)                                                         \
    do {                                                                  \
        kr0 = *(const uint4*)(kst + (size_t)(CH) * 64 * HD);              \
        kr1 = *(const uint4*)(kst + (size_t)(CH) * 64 * HD + 32 * HD);    \
        vr0 = *(const uint4*)(vst + (CH) * 64);                           \
        vr1 = *(const uint4*)(vst + (CH) * 64 + 32 * NSEQ);               \
    } while (0)
#define WRITER(BUF)                                                       \
    do {                                                                  \
        u16* kd = &KV[team][BUF][0][0];                                   \
        u16* vd = &KV[team][BUF][1][0];                                   \
        st16(kd + wi0, kr0); st16(kd + wi1, kr1);                         \
        st16(vd + wi0, vr0); st16(vd + wi1, vr1);                         \
    } while (0)

    // mask planes (q-innermost): plane = chg*4 + tile*2 + half, 16384 u16 each
    const u16* mrow0 = Madd3 + (size_t)(cbase * 4 + half) * 16384 + (size_t)(n0 + qA) * 16;
    const u16* mrow1 = mrow0 + 32768;
    // per-chunk stride = 4 planes = 65536 u16

    // prologue: stage chunk 0 into buf0; preload chunk-1 regs + masks(0)
    LOADR(0);
    WRITER(0);
    LOADR(1);
    uint4 m0a = *(const uint4*)(mrow0);
    uint4 m0b = *(const uint4*)(mrow0 + 8);
    uint4 m1a = *(const uint4*)(mrow1);
    uint4 m1b = *(const uint4*)(mrow1 + 8);
    __syncthreads();

    float l = 0.f;
    f32x16 O0 = {}, O1 = {};

    // per-lane LDS row bases (66-u16 skewed rows)
    const int rb0 = l31 * 66, rb1 = (32 + l31) * 66;

    for (int ch = 0; ch < 8; ++ch) {
        const int cur = ch & 1;
        const u16* Kc = &KV[team][cur][0][0];
        const u16* Vc = &KV[team][cur][1][0];

        // stage regs (chunk ch+1) -> buf[1-cur]; then load regs for ch+2
        if (ch < 7) WRITER(1 - cur);
        if (ch < 6) LOADR(ch + 2);

        // ---- QK keys 0..31 (C-init = mask) ----
        f32x16 s0 = maskinit(m0a, m0b);
        __builtin_amdgcn_s_setprio(1);
#pragma unroll
        for (int s = 0; s < 4; ++s) {
            const int g = (s * 2 + half) * 8;
            bf16x8 ka = ldfrag(&Kc[rb0 + g]);
            s0 = MFMA32(ka, qb[s], s0);
        }
        __builtin_amdgcn_s_setprio(0);
        bf16x8 pb[2];
        l += sm_pack_half(s0, pb);

        // ---- PV keys 0..31 (sigma granules 0,1) ----
        __builtin_amdgcn_s_setprio(1);
#pragma unroll
        for (int s = 0; s < 2; ++s) {
            const int g = (s * 2 + half) * 8;
            bf16x8 va0 = ldfrag(&Vc[rb0 + g]);
            bf16x8 va1 = ldfrag(&Vc[rb1 + g]);
            O0 = MFMA32(va0, pb[s], O0);
            O1 = MFMA32(va1, pb[s], O1);
        }
        __builtin_amdgcn_s_setprio(0);

        // ---- QK keys 32..63 ----
        f32x16 s1 = maskinit(m1a, m1b);
        if (ch < 7) {   // reload masks for ch+1 (WAR after consumption)
            const u16* mn0 = mrow0 + (size_t)(ch + 1) * 65536;
            const u16* mn1 = mrow1 + (size_t)(ch + 1) * 65536;
            m0a = *(const uint4*)(mn0);  m0b = *(const uint4*)(mn0 + 8);
            m1a = *(const uint4*)(mn1);  m1b = *(const uint4*)(mn1 + 8);
        }
        __builtin_amdgcn_s_setprio(1);
#pragma unroll
        for (int s = 0; s < 4; ++s) {
            const int g = (s * 2 + half) * 8;
            bf16x8 ka = ldfrag(&Kc[rb1 + g]);
            s1 = MFMA32(ka, qb[s], s1);
        }
        __builtin_amdgcn_s_setprio(0);
        l += sm_pack_half(s1, pb);

        // ---- PV keys 32..63 (sigma granules 2,3) ----
        __builtin_amdgcn_s_setprio(1);
#pragma unroll
        for (int s = 2; s < 4; ++s) {
            const int g = (s * 2 + half) * 8;
            bf16x8 va0 = ldfrag(&Vc[rb0 + g]);
            bf16x8 va1 = ldfrag(&Vc[rb1 + g]);
            O0 = MFMA32(va0, pb[s - 2], O0);
            O1 = MFMA32(va1, pb[s - 2], O1);
        }
        __builtin_amdgcn_s_setprio(0);
        __syncthreads();
    }
#undef LOADR
#undef WRITER

    // ---- cross-team combine: no-max softmax => partials just add ----
    float4* Oex = (float4*)&KV[0][0][0][0];            // 32 KB
    float*  Lex = (float*)(&KV[0][0][0][0] + 16384);   // after 32 KB

    if (team == 1) {
#pragma unroll
        for (int g = 0; g < 4; ++g) {
            float4 t;
            t.x = O0[4 * g + 0]; t.y = O0[4 * g + 1];
            t.z = O0[4 * g + 2]; t.w = O0[4 * g + 3];
            Oex[(j * 8 + g) * 64 + lane] = t;
            t.x = O1[4 * g + 0]; t.y = O1[4 * g + 1];
            t.z = O1[4 * g + 2]; t.w = O1[4 * g + 3];
            Oex[(j * 8 + 4 + g) * 64 + lane] = t;
        }
        Lex[j * 64 + lane] = l;
    }
    __syncthreads();
    if (team == 0) {
        l += Lex[j * 64 + lane];
#pragma unroll
        for (int g = 0; g < 4; ++g) {
            float4 t0 = Oex[(j * 8 + g) * 64 + lane];
            float4 t1 = Oex[(j * 8 + 4 + g) * 64 + lane];
            O0[4 * g + 0] += t0.x; O0[4 * g + 1] += t0.y;
            O0[4 * g + 2] += t0.z; O0[4 * g + 3] += t0.w;
            O1[4 * g + 0] += t1.x; O1[4 * g + 1] += t1.y;
            O1[4 * g + 2] += t1.z; O1[4 * g + 3] += t1.w;
        }

        // lanes l and l+32 hold disjoint key subsets of the same q
        l += __shfl_xor(l, 32, 64);
        const float inv = 1.0f / l;

        float* orow = out + (rowbase + n0 + qA) * HD + colbase;
#pragma unroll
        for (int g = 0; g < 4; ++g) {
            const int d0 = 4 * half + 8 * g;
            float4 a0, a1;
            a0.x = O0[4 * g + 0] * inv; a0.y = O0[4 * g + 1] * inv;
            a0.z = O0[4 * g + 2] * inv; a0.w = O0[4 * g + 3] * inv;
            a1.x = O1[4 * g + 0] * inv; a1.y = O1[4 * g + 1] * inv;
            a1.z = O1[4 * g + 2] * inv; a1.w = O1[4 * g + 3] * inv;
            *(float4*)(orow + d0)      = a0;
            *(float4*)(orow + 32 + d0) = a1;
        }
    }
}

// ============================================================
extern "C" void kernel_launch(void* const* d_in, const int* in_sizes, int n_in,
                              void* d_out, int out_size, void* d_ws, size_t ws_size,
                              hipStream_t stream) {
    const int*   adj = (const int*)d_in[0];
    const float* h   = (const float*)d_in[1];
    const float* Wq  = (const float*)d_in[2];
    const float* bq  = (const float*)d_in[3];
    const float* Wk  = (const float*)d_in[4];
    const float* bk  = (const float*)d_in[5];
    const float* Wv  = (const float*)d_in[6];
    const float* bv  = (const float*)d_in[7];
    float* outp = (float*)d_out;

    u16* Wt    = (u16*)d_ws;                                 // 3*512*256 u16
    u16* Qg    = Wt + (size_t)3 * HD * IN_DIM;               // 4 Mi u16 each
    u16* Kg    = Qg + (size_t)BATCH * NSEQ * HD;
    u16* Vtg   = Kg + (size_t)BATCH * NSEQ * HD;
    u16* Madd3 = Vtg + (size_t)BATCH * NSEQ * HD;            // 1 Mi u16 (2 MB)
    u16* hb    = Madd3 + (size_t)NSEQ * NSEQ;                // 2 Mi u16 (4 MB)
    (void)ws_size;

    wtrans_kernel<<<224, 256, 0, stream>>>(Wq, Wk, Wv, h, Wt, hb);
    gemm_mask_kernel<<<dim3(BATCH * NSEQ / 64, 10), 256, 0, stream>>>(
        hb, Wt, adj, bq, bk, bv, Qg, Kg, Vtg, Madd3);
    attn_kernel<<<dim3(BATCH * NHEADS, NSEQ / 128), 512, 0, stream>>>(
        Madd3, Qg, Kg, Vtg, outp);
}

// Round 12
// 121.164 us; speedup vs baseline: 1.2729x; 1.2729x over previous
//
#include <hip/hip_runtime.h>
#include <hip/hip_bf16.h>
#include <math.h>

#define IN_DIM 256
#define HD     512   // NUM_HEADS * OUT_DIM
#define NHEADS 8
#define DH     64
#define NSEQ   1024
#define BATCH  8

#define QSCALE 0.18033688011112042f   // 0.125 * log2(e): S in log2 domain

typedef unsigned short u16;
typedef unsigned int   u32;
typedef short bf16x8 __attribute__((ext_vector_type(8)));
typedef float f32x4  __attribute__((ext_vector_type(4)));
typedef float f32x16 __attribute__((ext_vector_type(16)));
typedef unsigned int u32x2 __attribute__((ext_vector_type(2)));

#if __has_builtin(__builtin_amdgcn_exp2f)
#define EXP2(x) __builtin_amdgcn_exp2f(x)
#else
#define EXP2(x) __expf(0.69314718056f * (x))
#endif

static __device__ __forceinline__ u16 f2bf(float x) {
    u32 u = __builtin_bit_cast(u32, x);
    u += 0x7FFFu + ((u >> 16) & 1u);     // RNE
    return (u16)(u >> 16);
}
static __device__ __forceinline__ u32 pk(u16 a, u16 b) {
    return (u32)a | ((u32)b << 16);
}
static __device__ __forceinline__ u32 cvtpk(float a, float b) {
    __hip_bfloat162 t = __float22bfloat162_rn(make_float2(a, b));
    u32 r; __builtin_memcpy(&r, &t, 4);
    return r;
}
// 16 bf16 (two uint4) -> f32x16 C-init
static __device__ __forceinline__ f32x16 maskinit(uint4 a, uint4 b) {
    f32x16 c;
    u32 ws[8] = {a.x, a.y, a.z, a.w, b.x, b.y, b.z, b.w};
#pragma unroll
    for (int i = 0; i < 8; ++i) {
        c[2 * i]     = __builtin_bit_cast(float, ws[i] << 16);
        c[2 * i + 1] = __builtin_bit_cast(float, ws[i] & 0xFFFF0000u);
    }
    return c;
}

// permlane32_swap: a' = [a_lo | b_lo], b' = [a_hi | b_hi] (32-lane rows)
static __device__ __forceinline__ void pswap(u32 &a, u32 &b) {
#if __has_builtin(__builtin_amdgcn_permlane32_swap)
    u32x2 r = __builtin_amdgcn_permlane32_swap(a, b, false, false);
    a = r.x; b = r.y;
#else
    const bool hi = (threadIdx.x & 32) != 0;
    u32 as = (u32)__shfl_xor((int)a, 32, 64);
    u32 bs = (u32)__shfl_xor((int)b, 32, 64);
    u32 na = hi ? bs : a;
    u32 nb = hi ? b  : as;
    a = na; b = nb;
#endif
}

#define MFMA32(a, b, c) __builtin_amdgcn_mfma_f32_32x32x16_bf16(a, b, c, 0, 0, 0)

// async global->LDS, 16 B/lane; LDS dest is wave-uniform base + lane*16
#define GLOAD16(G, L)                                                          \
    __builtin_amdgcn_global_load_lds(                                          \
        (const __attribute__((address_space(1))) unsigned int*)(const void*)(G),\
        (__attribute__((address_space(3))) unsigned int*)(void*)(L), 16, 0, 0)

// exp2 of ONE 32-key S^T tile, tree-sum, pack to bf16, permlane-exchange:
// pb[0], pb[1] are the B-frags for the two 16-key MFMA steps of this tile.
static __device__ __forceinline__ float sm_pack_half(const f32x16 st, bf16x8* pb) {
    float p[16];
#pragma unroll
    for (int r = 0; r < 16; ++r) p[r] = EXP2(st[r]);
    float t = (((p[0] + p[1]) + (p[2] + p[3])) + ((p[4] + p[5]) + (p[6] + p[7])))
            + (((p[8] + p[9]) + (p[10] + p[11])) + ((p[12] + p[13]) + (p[14] + p[15])));
    uint4 w0, w1;
    w0.x = cvtpk(p[0], p[1]);   w0.y = cvtpk(p[2], p[3]);
    w0.z = cvtpk(p[4], p[5]);   w0.w = cvtpk(p[6], p[7]);
    w1.x = cvtpk(p[8], p[9]);   w1.y = cvtpk(p[10], p[11]);
    w1.z = cvtpk(p[12], p[13]); w1.w = cvtpk(p[14], p[15]);
    pswap(w0.x, w1.x); pswap(w0.y, w1.y); pswap(w0.z, w1.z); pswap(w0.w, w1.w);
    pb[0] = __builtin_bit_cast(bf16x8, w0);
    pb[1] = __builtin_bit_cast(bf16x8, w1);
    return t;
}

// ============================================================
// W transpose + h->bf16: 224 blocks.
//  bid<96:  W [K=256][N=512] fp32 -> Wt [N][K] bf16 (x3)
//  bid>=96: h fp32 -> hb bf16 (elementwise, coalesced)
// ============================================================
__global__ __launch_bounds__(256)
void wtrans_kernel(const float* __restrict__ Wq, const float* __restrict__ Wk,
                   const float* __restrict__ Wv, const float* __restrict__ h,
                   u16* __restrict__ Wt, u16* __restrict__ hb)
{
    __shared__ float tile[64 * 65];
    const int bid = blockIdx.x, tid = threadIdx.x;

    if (bid >= 96) {
        const int ab = bid - 96;
        const float4* hs = (const float4*)h;
        uint2* hd = (uint2*)hb;
        const int base = ab * 4096 + tid;
#pragma unroll
        for (int j = 0; j < 16; ++j) {
            float4 v = hs[base + j * 256];
            uint2 o;
            o.x = cvtpk(v.x, v.y);
            o.y = cvtpk(v.z, v.w);
            hd[base + j * 256] = o;
        }
        return;
    }

    const int k0 = (bid & 3) * 64, n0 = ((bid >> 2) & 7) * 64, wsel = bid >> 5;
    const float* W = (wsel == 0) ? Wq : (wsel == 1) ? Wk : Wv;
    u16* Out = Wt + (size_t)wsel * HD * IN_DIM;

    const int r = tid >> 2, c0 = (tid & 3) * 16;
#pragma unroll
    for (int j = 0; j < 16; j += 4) {
        float4 v = *(const float4*)(W + (size_t)(k0 + r) * HD + n0 + c0 + j);
        tile[r * 65 + c0 + j + 0] = v.x; tile[r * 65 + c0 + j + 1] = v.y;
        tile[r * 65 + c0 + j + 2] = v.z; tile[r * 65 + c0 + j + 3] = v.w;
    }
    __syncthreads();
    const int n = tid >> 2, ks = (tid & 3) * 16;
    u16 o[16];
#pragma unroll
    for (int j = 0; j < 16; ++j) o[j] = f2bf(tile[(ks + j) * 65 + n]);
    uint4 u0, u1;
    u0.x = pk(o[0], o[1]);   u0.y = pk(o[2], o[3]);
    u0.z = pk(o[4], o[5]);   u0.w = pk(o[6], o[7]);
    u1.x = pk(o[8], o[9]);   u1.y = pk(o[10], o[11]);
    u1.z = pk(o[12], o[13]); u1.w = pk(o[14], o[15]);
    u16* dst = Out + (size_t)(n0 + n) * IN_DIM + k0 + ks;
    *(uint4*)(dst) = u0;
    *(uint4*)(dst + 8) = u1;
}

// ============================================================
// Fused QKV GEMM + mask build, grid (128, 10):
//  y<8:  GEMM m-tile 64 x head y — 32x32x16 MFMA; DMA-staged A/B
//        (global_load_lds, inverse-swizzled source), double-buffered,
//        one barrier per K-step, fully unrolled.
//  y>=8: adj -> mask bf16 {0,-3.39e38} q-innermost:
//        Madd3[plane = ch*4 + (p0/16)][q 1024][16], plane = 32 KB.
// ============================================================
__global__ __launch_bounds__(256, 2)
void gemm_mask_kernel(const u16* __restrict__ hb, const u16* __restrict__ Wt,
                      const int* __restrict__ adj,
                      const float* __restrict__ bq, const float* __restrict__ bk,
                      const float* __restrict__ bv,
                      u16* __restrict__ Qg, u16* __restrict__ Kg,
                      u16* __restrict__ Vtg, u16* __restrict__ Madd3)
{
    __shared__ __align__(16) u16 lds[32768];
    const int tid = threadIdx.x;

    if (blockIdx.y >= 8) {
        int* tile = (int*)lds;               // [64][65] ints
        const int abid = (blockIdx.y - 8) * 128 + blockIdx.x;   // 0..255
        const int tR = abid >> 4, tC = abid & 15;
        const int r = tid >> 2, cg = (tid & 3) * 16;
        const int* src = adj + (size_t)(tR * 64 + r) * NSEQ + tC * 64 + cg;
#pragma unroll
        for (int j = 0; j < 16; j += 4) {
            int4 a = *(const int4*)(src + j);
            tile[r * 65 + cg + j + 0] = a.x; tile[r * 65 + cg + j + 1] = a.y;
            tile[r * 65 + cg + j + 2] = a.z; tile[r * 65 + cg + j + 3] = a.w;
        }
        __syncthreads();
        const int q = tid >> 2, g4 = tid & 3, p0 = g4 * 16;
        u16 o[16];
#pragma unroll
        for (int j = 0; j < 16; ++j) {
            const int p = p0 + j;
            const int c = 32 * (p >> 5) + (p & 3) + 4 * ((p >> 4) & 1) + 8 * ((p >> 2) & 3);
            o[j] = (tile[q * 65 + c] == 0) ? (u16)0xFF7F : (u16)0;
        }
        uint4 u0, u1;
        u0.x = pk(o[0], o[1]);   u0.y = pk(o[2], o[3]);
        u0.z = pk(o[4], o[5]);   u0.w = pk(o[6], o[7]);
        u1.x = pk(o[8], o[9]);   u1.y = pk(o[10], o[11]);
        u1.z = pk(o[12], o[13]); u1.w = pk(o[14], o[15]);
        u16* dst = Madd3 + ((size_t)(tC * 4 + g4) * 1024 + tR * 64 + q) * 16;
        *(uint4*)(dst) = u0;
        *(uint4*)(dst + 8) = u1;
        return;
    }

    const int m0 = blockIdx.x * 64;
    const int hh = blockIdx.y;
    const int n0 = hh * 64;

    const int w = tid >> 6, lane = tid & 63;
    const int l31 = lane & 31, half = lane >> 5;
    const int mh = w & 1, nh = w >> 1;
    const int s7 = l31 & 7;

    const int lrow = lane >> 3, lgran = (lane & 7) ^ lrow;
    const int r0 = w * 16;
    const u16* ag = hb + (size_t)(m0 + r0 + lrow) * IN_DIM + lgran * 8;
    const u16* bg = Wt + (size_t)(n0 + r0 + lrow) * IN_DIM + lgran * 8;

#define STAGE_G(BUF, KK)                                                        \
    do {                                                                        \
        u16* a0 = lds + (BUF) * 4096 + r0 * 64;                                 \
        u16* b0 = lds + 8192 + (BUF) * 12288 + r0 * 64;                         \
        GLOAD16(ag + (KK) * 64,                                    a0);         \
        GLOAD16(ag + (KK) * 64 + 8 * IN_DIM,                       a0 + 512);   \
        GLOAD16(bg + (KK) * 64,                                    b0);         \
        GLOAD16(bg + (KK) * 64 + 8 * IN_DIM,                       b0 + 512);   \
        GLOAD16(bg + (KK) * 64 + (size_t)HD * IN_DIM,              b0 + 4096);  \
        GLOAD16(bg + (KK) * 64 + (size_t)HD * IN_DIM + 8 * IN_DIM, b0 + 4608);  \
        GLOAD16(bg + (KK) * 64 + (size_t)2 * HD * IN_DIM,          b0 + 8192);  \
        GLOAD16(bg + (KK) * 64 + (size_t)2 * HD * IN_DIM + 8 * IN_DIM, b0 + 8704); \
    } while (0)

    f32x16 acc[3] = {};   // Q, K, V 32x32 tiles
    const int arow = (32 * mh + l31) * 64;
    const int brow = (32 * nh + l31) * 64;

    STAGE_G(0, 0);
#pragma unroll
    for (int kk = 0; kk < 4; ++kk) {
        const int cur = kk & 1;
        __syncthreads();
        if (kk < 3) STAGE_G(1 - cur, kk + 1);
        const u16* Ac = lds + cur * 4096;
        const u16* Bc = lds + 8192 + cur * 12288;
#pragma unroll
        for (int s = 0; s < 4; ++s) {
            const int g = ((s * 2 + half) ^ s7) * 8;
            bf16x8 a = *(const bf16x8*)&Ac[arow + g];
#pragma unroll
            for (int wh = 0; wh < 3; ++wh) {
                bf16x8 b = *(const bf16x8*)&Bc[wh * 4096 + brow + g];
                acc[wh] = __builtin_amdgcn_mfma_f32_32x32x16_bf16(a, b, acc[wh], 0, 0, 0);
            }
        }
    }
#undef STAGE_G

    for (int which = 0; which < 2; ++which) {
        u16* T = lds;   // [64][72]
        const float* bias = (which == 0) ? bq : bk;
        u16* Out = (which == 0) ? Qg : Kg;
        const float scale = (which == 0) ? QSCALE : 1.0f;
        const float bvv = bias[n0 + 32 * nh + l31];
        __syncthreads();
#pragma unroll
        for (int r = 0; r < 16; ++r) {
            const int row = 32 * mh + 4 * half + (r & 3) + 8 * (r >> 2);
            T[row * 72 + 32 * nh + l31] = f2bf((acc[which][r] + bvv) * scale);
        }
        __syncthreads();
        const int row = tid >> 2, qc = (tid & 3) * 16;
        u16* dst = Out + (size_t)(m0 + row) * HD + n0 + qc;
        const u16* srcT = &T[row * 72 + qc];
        *(uint4*)(dst)     = *(const uint4*)(srcT);
        *(uint4*)(dst + 8) = *(const uint4*)(srcT + 8);
    }

    {
        u16* T = lds;   // [64][72]  [d][pos]
        const int d = 32 * nh + l31;
        const float bvv = bv[n0 + d];
        __syncthreads();
#pragma unroll
        for (int g = 0; g < 4; ++g) {
            ushort4 o;
            o.x = f2bf(acc[2][4 * g + 0] + bvv);
            o.y = f2bf(acc[2][4 * g + 1] + bvv);
            o.z = f2bf(acc[2][4 * g + 2] + bvv);
            o.w = f2bf(acc[2][4 * g + 3] + bvv);
            *(ushort4*)&T[d * 72 + 32 * mh + 16 * half + 4 * g] = o;
        }
        __syncthreads();
        const int b = m0 >> 10, nloc = m0 & 1023;
        const int dd = tid >> 2, c = (tid & 3) * 16;
        u16* dst = Vtg + ((size_t)(b * NHEADS + hh) * DH + dd) * NSEQ + nloc + c;
        *(uint4*)(dst)     = *(uint4*)&T[dd * 72 + c];
        *(uint4*)(dst + 8) = *(uint4*)&T[dd * 72 + c + 8];
    }
}

// ============================================================
// Fused masked attention, 32x32x16 MFMA, no-max softmax.
// Round-12 = round-9 best structure + setprio (T5), z=1.
//  Evidence: r10 z=2 diagnostic ran 60.3us for 2x work (~30us/unit) vs
//  ~36us for r9 without setprio -> T5 pays in this structure (m191
//  prior + local measurement). r11's conflict-fix-by-register-staging
//  REFUTED: spilled 115MB at the 128-VGPR cap (67us). The 4-way LDS
//  conflict (64 cy/wave-chunk) is structural with 16B-DMA staging and
//  accepted as cheaper than any alternative measured.
//  Structure: 512 thr, team = w>>2 key-halves, qrep=1, 4 waves/SIMD,
//  DMA K/V staging (zero staging VGPRs), half-chunk softmax, permlane
//  P-exchange, q-innermost coalesced mask planes.
// ============================================================
__global__ __launch_bounds__(512, 4)
void attn_kernel(const u16* __restrict__ Madd3, const u16* __restrict__ Qg,
                 const u16* __restrict__ Kg, const u16* __restrict__ Vtg,
                 float* __restrict__ out)
{
    __shared__ __align__(16) u16 Ks[2][2][4096];   // [team][buf][64 x 64]
    __shared__ __align__(16) u16 Vs[2][2][4096];   // [d][cpos(m)]

    const int tid = threadIdx.x;
    const int w = tid >> 6, lane = tid & 63;
    const int team = w >> 2, j = w & 3;
    const int l31 = lane & 31, half = lane >> 5;
    const int bh = blockIdx.x, qt = blockIdx.y;
    const int b = bh >> 3;
    const int n0 = qt * 128;
    const size_t rowbase = (size_t)b * NSEQ;
    const int colbase = (bh & 7) * DH;
    const int q7 = l31 & 7;
    const int qA = j * 32 + l31;          // block-local q row (wave's tile)
    const int cbase = team * 8;           // team's first key chunk

    // Q B-frags (bf16, pre-scaled): B[k][q=l31]
    const u16* qga = Qg + (rowbase + n0 + qA) * HD + colbase;
    bf16x8 qb[4];
#pragma unroll
    for (int s = 0; s < 4; ++s)
        qb[s] = *(const bf16x8*)(qga + s * 16 + half * 8);

    // ---- async staging geometry ----
    const int lrow = lane >> 3, lgran = (lane & 7) ^ lrow;
    const int br0 = j * 16, br1 = j * 16 + 8;
    const u16* kg0 = Kg + (rowbase + cbase * 64 + br0 + lrow) * HD + colbase + lgran * 8;
    const u16* kg1 = kg0 + (size_t)8 * HD;
    const u16* vg0 = Vtg + ((size_t)bh * DH + br0 + lrow) * NSEQ + cbase * 64 + lgran * 8;
    const u16* vg1 = vg0 + (size_t)8 * NSEQ;

#define STAGE(BUF, CH)                                                   \
    do {                                                                 \
        GLOAD16(kg0 + (size_t)(CH) * 64 * HD, &Ks[team][BUF][br0 * 64]); \
        GLOAD16(kg1 + (size_t)(CH) * 64 * HD, &Ks[team][BUF][br1 * 64]); \
        GLOAD16(vg0 + (CH) * 64,              &Vs[team][BUF][br0 * 64]); \
        GLOAD16(vg1 + (CH) * 64,              &Vs[team][BUF][br1 * 64]); \
    } while (0)

    // mask planes (q-innermost): plane = chg*4 + tile*2 + half, 16384 u16 each
    const u16* mrow0 = Madd3 + (size_t)(cbase * 4 + half) * 16384 + (size_t)(n0 + qA) * 16;
    const u16* mrow1 = mrow0 + 32768;
    // per-chunk stride = 4 planes = 65536 u16

    // prologue: stage chunk 0, load chunk-0 masks; barrier drains DMA
    STAGE(0, 0);
    uint4 m0a = *(const uint4*)(mrow0);
    uint4 m0b = *(const uint4*)(mrow0 + 8);
    uint4 m1a = *(const uint4*)(mrow1);
    uint4 m1b = *(const uint4*)(mrow1 + 8);
    __syncthreads();

    float l = 0.f;
    f32x16 O0 = {}, O1 = {};

    for (int ch = 0; ch < 8; ++ch) {
        const int cur = ch & 1;
        const u16* Kc = &Ks[team][cur][0];
        const u16* Vc = &Vs[team][cur][0];

        // issue next chunk's DMA now: full chunk of latency cover, the
        // end-of-chunk barrier is the vmcnt drain.
        if (ch < 7) STAGE(1 - cur, ch + 1);

        // ---- QK keys 0..31 (C-init = mask) ----
        f32x16 s0 = maskinit(m0a, m0b);
        __builtin_amdgcn_s_setprio(1);
#pragma unroll
        for (int s = 0; s < 4; ++s) {
            const int g = ((s * 2 + half) ^ q7) * 8;
            bf16x8 ka = *(const bf16x8*)&Kc[l31 * 64 + g];
            s0 = MFMA32(ka, qb[s], s0);
        }
        __builtin_amdgcn_s_setprio(0);
        bf16x8 pb[2];
        l += sm_pack_half(s0, pb);

        // ---- PV keys 0..31 (sigma granules 0,1) ----
        __builtin_amdgcn_s_setprio(1);
#pragma unroll
        for (int s = 0; s < 2; ++s) {
            const int g = ((s * 2 + half) ^ q7) * 8;
            bf16x8 va0 = *(const bf16x8*)&Vc[l31 * 64 + g];
            bf16x8 va1 = *(const bf16x8*)&Vc[(32 + l31) * 64 + g];
            O0 = MFMA32(va0, pb[s], O0);
            O1 = MFMA32(va1, pb[s], O1);
        }
        __builtin_amdgcn_s_setprio(0);

        // ---- QK keys 32..63 ----
        f32x16 s1 = maskinit(m1a, m1b);
        if (ch < 7) {   // reload masks for ch+1 into the SAME regs (WAR)
            const u16* mn0 = mrow0 + (size_t)(ch + 1) * 65536;
            const u16* mn1 = mrow1 + (size_t)(ch + 1) * 65536;
            m0a = *(const uint4*)(mn0);  m0b = *(const uint4*)(mn0 + 8);
            m1a = *(const uint4*)(mn1);  m1b = *(const uint4*)(mn1 + 8);
        }
        __builtin_amdgcn_s_setprio(1);
#pragma unroll
        for (int s = 0; s < 4; ++s) {
            const int g = ((s * 2 + half) ^ q7) * 8;
            bf16x8 ka = *(const bf16x8*)&Kc[(32 + l31) * 64 + g];
            s1 = MFMA32(ka, qb[s], s1);
        }
        __builtin_amdgcn_s_setprio(0);
        l += sm_pack_half(s1, pb);

        // ---- PV keys 32..63 (sigma granules 2,3) ----
        __builtin_amdgcn_s_setprio(1);
#pragma unroll
        for (int s = 2; s < 4; ++s) {
            const int g = ((s * 2 + half) ^ q7) * 8;
            bf16x8 va0 = *(const bf16x8*)&Vc[l31 * 64 + g];
            bf16x8 va1 = *(const bf16x8*)&Vc[(32 + l31) * 64 + g];
            O0 = MFMA32(va0, pb[s - 2], O0);
            O1 = MFMA32(va1, pb[s - 2], O1);
        }
        __builtin_amdgcn_s_setprio(0);
        __syncthreads();
    }
#undef STAGE

    // ---- cross-team combine: no-max softmax => partials just add ----
    float4* Oex = (float4*)&Ks[0][0][0];   // 2048 float4 = 32 KB
    float*  Lex = (float*)&Vs[0][0][0];

    if (team == 1) {
#pragma unroll
        for (int g = 0; g < 4; ++g) {
            float4 t;
            t.x = O0[4 * g + 0]; t.y = O0[4 * g + 1];
            t.z = O0[4 * g + 2]; t.w = O0[4 * g + 3];
            Oex[(j * 8 + g) * 64 + lane] = t;
            t.x = O1[4 * g + 0]; t.y = O1[4 * g + 1];
            t.z = O1[4 * g + 2]; t.w = O1[4 * g + 3];
            Oex[(j * 8 + 4 + g) * 64 + lane] = t;
        }
        Lex[j * 64 + lane] = l;
    }
    __syncthreads();
    if (team == 0) {
        l += Lex[j * 64 + lane];
#pragma unroll
        for (int g = 0; g < 4; ++g) {
            float4 t0 = Oex[(j * 8 + g) * 64 + lane];
            float4 t1 = Oex[(j * 8 + 4 + g) * 64 + lane];
            O0[4 * g + 0] += t0.x; O0[4 * g + 1] += t0.y;
            O0[4 * g + 2] += t0.z; O0[4 * g + 3] += t0.w;
            O1[4 * g + 0] += t1.x; O1[4 * g + 1] += t1.y;
            O1[4 * g + 2] += t1.z; O1[4 * g + 3] += t1.w;
        }

        // lanes l and l+32 hold disjoint key subsets of the same q
        l += __shfl_xor(l, 32, 64);
        const float inv = 1.0f / l;

        float* orow = out + (rowbase + n0 + qA) * HD + colbase;
#pragma unroll
        for (int g = 0; g < 4; ++g) {
            const int d0 = 4 * half + 8 * g;
            float4 a0, a1;
            a0.x = O0[4 * g + 0] * inv; a0.y = O0[4 * g + 1] * inv;
            a0.z = O0[4 * g + 2] * inv; a0.w = O0[4 * g + 3] * inv;
            a1.x = O1[4 * g + 0] * inv; a1.y = O1[4 * g + 1] * inv;
            a1.z = O1[4 * g + 2] * inv; a1.w = O1[4 * g + 3] * inv;
            *(float4*)(orow + d0)      = a0;
            *(float4*)(orow + 32 + d0) = a1;
        }
    }
}

// ============================================================
extern "C" void kernel_launch(void* const* d_in, const int* in_sizes, int n_in,
                              void* d_out, int out_size, void* d_ws, size_t ws_size,
                              hipStream_t stream) {
    const int*   adj = (const int*)d_in[0];
    const float* h   = (const float*)d_in[1];
    const float* Wq  = (const float*)d_in[2];
    const float* bq  = (const float*)d_in[3];
    const float* Wk  = (const float*)d_in[4];
    const float* bk  = (const float*)d_in[5];
    const float* Wv  = (const float*)d_in[6];
    const float* bv  = (const float*)d_in[7];
    float* outp = (float*)d_out;

    u16* Wt    = (u16*)d_ws;                                 // 3*512*256 u16
    u16* Qg    = Wt + (size_t)3 * HD * IN_DIM;               // 4 Mi u16 each
    u16* Kg    = Qg + (size_t)BATCH * NSEQ * HD;
    u16* Vtg   = Kg + (size_t)BATCH * NSEQ * HD;
    u16* Madd3 = Vtg + (size_t)BATCH * NSEQ * HD;            // 1 Mi u16 (2 MB)
    u16* hb    = Madd3 + (size_t)NSEQ * NSEQ;                // 2 Mi u16 (4 MB)
    (void)ws_size;

    wtrans_kernel<<<224, 256, 0, stream>>>(Wq, Wk, Wv, h, Wt, hb);
    gemm_mask_kernel<<<dim3(BATCH * NSEQ / 64, 10), 256, 0, stream>>>(
        hb, Wt, adj, bq, bk, bv, Qg, Kg, Vtg, Madd3);
    attn_kernel<<<dim3(BATCH * NHEADS, NSEQ / 128), 512, 0, stream>>>(
        Madd3, Qg, Kg, Vtg, outp);
}